// Round 4
// baseline (1031.779 us; speedup 1.0000x reference)
//
#include <hip/hip_runtime.h>
#include <hip/hip_bf16.h>

#define N_NODES 2048
#define N_EDGES 65536
#define D_IN    64
#define D_OUT   64
#define GAT_EPS 1e-6f

typedef unsigned short u16;
typedef unsigned int   u32;
typedef __attribute__((ext_vector_type(8))) short frag8;   // 8 bf16 = 4 VGPRs
typedef __attribute__((ext_vector_type(4))) float f32x4;

__device__ __forceinline__ u16 f2bf(float f) {
    union { u32 u; float f; } x; x.f = f;
    u32 lsb = (x.u >> 16) & 1u;
    x.u += 0x7fffu + lsb;           // round-to-nearest-even
    return (u16)(x.u >> 16);
}

// ---------------- index extraction from one-hot [N,E] f32 ----------------
// 16384 blocks: [0,8192) scan src, [8192,16384) scan tgt. Each thread does
// 16 coalesced uint4 loads in two batches of 8 (8 KB in flight per wave),
// with ONE rarely-taken OR-test per batch instead of per-load branches.
// Blocks < 520 also zero a_sum + out_acc (133120 f32); stream order makes
// these visible to k_fused.
__global__ void k_extract(const uint4* __restrict__ src, const uint4* __restrict__ tgt,
                          int* __restrict__ sidx, int* __restrict__ tidx,
                          float* __restrict__ zero_base) {
    u32 b = blockIdx.x, tid = threadIdx.x;
    if (b < 520u) {
        u32 zi = b * 256u + tid;
        if (zi < 133120u) zero_base[zi] = 0.0f;
    }
    const uint4* m; int* idx;
    if (b < 8192u) { m = src; idx = sidx; }
    else           { m = tgt; idx = tidx; b -= 8192u; }
    u32 t0 = b * 256u + tid;
    const u32 S = 2097152u;                   // grid stride in uint4
    #pragma unroll
    for (int g = 0; g < 2; ++g) {
        uint4 v[8];
        #pragma unroll
        for (int i = 0; i < 8; ++i) v[i] = m[t0 + (u32)(g * 8 + i) * S];
        u32 any = 0;
        #pragma unroll
        for (int i = 0; i < 8; ++i) any |= v[i].x | v[i].y | v[i].z | v[i].w;
        if (any) {                            // taken ~1.5% of the time
            #pragma unroll
            for (int i = 0; i < 8; ++i) {
                if (v[i].x | v[i].y | v[i].z | v[i].w) {
                    u32 elem = (t0 + (u32)(g * 8 + i) * S) * 4u;   // n*65536+e
                    int n = (int)(elem >> 16);
                    int e = (int)(elem & 65535u);
                    if (v[i].x) idx[e]     = n;
                    if (v[i].y) idx[e + 1] = n;
                    if (v[i].z) idx[e + 2] = n;
                    if (v[i].w) idx[e + 3] = n;
                }
            }
        }
    }
}

// ---------------- fused: score + exp + a_sum, MFMA GEMM, scatter ----------
// (unchanged from round 3, which passed at absmax 0.0156)
__global__ void __launch_bounds__(256) k_fused(
        const float* __restrict__ x,
        const int* __restrict__ sidx, const int* __restrict__ tidx,
        const float* __restrict__ Wf, const float* __restrict__ bf,
        const float* __restrict__ Ww, const float* __restrict__ bw,
        float* __restrict__ a_sum, float* __restrict__ out_acc) {
    __shared__ u16 wt[D_OUT * 2 * D_IN];      // wt[d][k], k contiguous (16KB)
    __shared__ float ww[2 * D_IN];            // attention weights f32
    int tid = threadIdx.x;
    if (tid < 2 * D_IN) ww[tid] = Ww[tid];
    for (int i = tid; i < 2 * D_IN * D_OUT; i += 256) {
        int k = i >> 6, d = i & 63;           // Wf is [128][64] row-major f32
        wt[d * 128 + k] = f2bf(Wf[i]);
    }
    __syncthreads();

    int wave = tid >> 6, lane = tid & 63;
    int q = lane >> 4, r = lane & 15;
    int e0 = blockIdx.x * 64 + wave * 16;

    int s_r = sidx[e0 + r] & (N_NODES - 1);   // defensive clamp
    int t_r = tidx[e0 + r] & (N_NODES - 1);
    const float* xs = x + s_r * D_IN;
    const float* xt = x + t_r * D_IN;

    // A operand: lane holds A[m = lane&15][k = q*8 + j]; h = [x[s], x[t]]
    frag8 afr[4];
    float part = 0.0f;
    #pragma unroll
    for (int c = 0; c < 4; ++c) {
        const float* base = (c < 2 ? xs : xt) + (c & 1) * 32 + q * 8;
        int kb = (c >> 1) * 64 + (c & 1) * 32 + q * 8;
        float4 lo = *(const float4*)(base);
        float4 hi = *(const float4*)(base + 4);
        part += lo.x * ww[kb]     + lo.y * ww[kb + 1]
              + lo.z * ww[kb + 2] + lo.w * ww[kb + 3]
              + hi.x * ww[kb + 4] + hi.y * ww[kb + 5]
              + hi.z * ww[kb + 6] + hi.w * ww[kb + 7];
        frag8 f;
        f[0] = (short)f2bf(lo.x); f[1] = (short)f2bf(lo.y);
        f[2] = (short)f2bf(lo.z); f[3] = (short)f2bf(lo.w);
        f[4] = (short)f2bf(hi.x); f[5] = (short)f2bf(hi.y);
        f[6] = (short)f2bf(hi.z); f[7] = (short)f2bf(hi.w);
        afr[c] = f;
    }
    // reduce the score over the 4 lanes sharing r (q = 0..3)
    part += __shfl_xor(part, 16);
    part += __shfl_xor(part, 32);
    float ae = expf(part + bw[0]);            // unshifted exp (shift cancels)
    if (lane < 16) atomicAdd(&a_sum[t_r], ae);

    f32x4 acc[4] = { {0,0,0,0}, {0,0,0,0}, {0,0,0,0}, {0,0,0,0} };
    #pragma unroll
    for (int c = 0; c < 4; ++c) {
        #pragma unroll
        for (int dt = 0; dt < 4; ++dt) {
            // B operand: lane holds B[k = q*8+j][n = lane&15] = Wf[k][dt*16+r]
            frag8 bfr = *(const frag8*)(&wt[(dt * 16 + r) * 128 + c * 32 + q * 8]);
            acc[dt] = __builtin_amdgcn_mfma_f32_16x16x32_bf16(afr[c], bfr, acc[dt], 0, 0, 0);
        }
    }

    // C/D layout: col = lane&15 (dim), row = q*4 + reg (edge)
    #pragma unroll
    for (int reg = 0; reg < 4; ++reg) {
        float w  = __shfl(ae,  q * 4 + reg);  // lane (q*4+reg) holds that edge
        int   tg = __shfl(t_r, q * 4 + reg);
        #pragma unroll
        for (int dt = 0; dt < 4; ++dt) {
            int d = dt * 16 + r;
            float y = acc[dt][reg] + bf[d];
            y = y > 0.0f ? y : 0.0f;
            atomicAdd(&out_acc[tg * D_OUT + d], y * w);
        }
    }
}

// ---------------- normalize: out = out_acc / (a_sum + eps) ----------------
__global__ void k_norm(const f32x4* __restrict__ out_acc, const float* __restrict__ a_sum,
                       f32x4* __restrict__ out) {
    int i = blockIdx.x * 256 + threadIdx.x;   // 32768 float4 groups
    float inv = 1.0f / (a_sum[i >> 4] + GAT_EPS);   // 16 float4 per node row
    f32x4 v = out_acc[i];
    out[i] = v * inv;
}

extern "C" void kernel_launch(void* const* d_in, const int* in_sizes, int n_in,
                              void* d_out, int out_size, void* d_ws, size_t ws_size,
                              hipStream_t stream) {
    const float* x   = (const float*)d_in[0];
    const float* src = (const float*)d_in[1];
    const float* tgt = (const float*)d_in[2];
    const float* Wf  = (const float*)d_in[3];
    const float* bf  = (const float*)d_in[4];
    const float* Ww  = (const float*)d_in[5];
    const float* bw  = (const float*)d_in[6];
    float* out = (float*)d_out;

    char* ws = (char*)d_ws;
    // ws layout: [a_sum 2048 f32 | out_acc 131072 f32 | sidx | tidx]
    float* a_sum   = (float*)(ws);
    float* out_acc = (float*)(ws + 8192);
    int*   sidx    = (int*)  (ws + 8192 + 524288);        // 532480
    int*   tidx    = (int*)  (ws + 532480 + 262144);      // 794624

    k_extract<<<16384, 256, 0, stream>>>((const uint4*)src, (const uint4*)tgt,
                                         sidx, tidx, (float*)ws);
    k_fused<<<N_EDGES / 64, 256, 0, stream>>>(x, sidx, tidx, Wf, bf, Ww, bw,
                                              a_sum, out_acc);
    k_norm<<<(N_NODES * D_OUT / 4) / 256, 256, 0, stream>>>(
        (const f32x4*)out_acc, a_sum, (f32x4*)out);
}

// Round 6
// 1013.315 us; speedup vs baseline: 1.0182x; 1.0182x over previous
//
#include <hip/hip_runtime.h>
#include <hip/hip_bf16.h>

#define N_NODES 2048
#define N_EDGES 65536
#define D_IN    64
#define D_OUT   64
#define GAT_EPS 1e-6f

typedef unsigned short u16;
typedef unsigned int   u32;
typedef unsigned long long u64;
typedef __attribute__((ext_vector_type(8))) short frag8;   // 8 bf16 = 4 VGPRs
typedef __attribute__((ext_vector_type(4))) float f32x4;

__device__ __forceinline__ u16 f2bf(float f) {
    union { u32 u; float f; } x; x.f = f;
    u32 lsb = (x.u >> 16) & 1u;
    x.u += 0x7fffu + lsb;           // round-to-nearest-even
    return (u16)(x.u >> 16);
}

// ---------------- index extraction from one-hot [N,E] f32 ----------------
// Round-3 measured-best config: 4096 blocks, 64 coalesced uint4 loads per
// thread, grid stride, unroll 4 (BW-bound; deeper batching regressed in r4).
// Pure writes: every sidx/tidx element is written exactly once per launch —
// no dependence on prior d_ws state.
__global__ void k_extract(const uint4* __restrict__ src, const uint4* __restrict__ tgt,
                          int* __restrict__ sidx, int* __restrict__ tidx) {
    u32 b = blockIdx.x, tid = threadIdx.x;
    const uint4* m; int* idx;
    if (b < 2048u) { m = src; idx = sidx; }
    else           { m = tgt; idx = tidx; b -= 2048u; }
    u32 t0 = b * 256u + tid;
    const u32 S = 524288u;                    // grid stride in uint4
    #pragma unroll 4
    for (u32 it = 0; it < 64u; ++it) {
        u32 t = t0 + it * S;                  // < N*E/4 = 33554432
        uint4 v = m[t];
        if (v.x | v.y | v.z | v.w) {
            u32 elem = t * 4u;                // flat n*65536 + e
            int n = (int)(elem >> 16);        // E = 65536
            int e = (int)(elem & 65535u);
            if (v.x) idx[e]     = n;
            if (v.y) idx[e + 1] = n;
            if (v.z) idx[e + 2] = n;
            if (v.w) idx[e + 3] = n;
        }
    }
}

// ---------------- per-edge: score + exp, MFMA GEMM, STORE (no atomics) ----
// Wave handles 16 edges x 64 dims. Writes ae[e] and P[e][d] = ae*relu(y)
// as plain stores; every element of both arrays is written every launch.
__global__ void __launch_bounds__(256) k_edges(
        const float* __restrict__ x,
        const int* __restrict__ sidx, const int* __restrict__ tidx,
        const float* __restrict__ Wf, const float* __restrict__ bf,
        const float* __restrict__ Ww, const float* __restrict__ bw,
        float* __restrict__ ae_out, float* __restrict__ P) {
    __shared__ u16 wt[D_OUT * 2 * D_IN];      // wt[d][k], k contiguous (16KB)
    __shared__ float ww[2 * D_IN];            // attention weights f32
    int tid = threadIdx.x;
    if (tid < 2 * D_IN) ww[tid] = Ww[tid];
    for (int i = tid; i < 2 * D_IN * D_OUT; i += 256) {
        int k = i >> 6, d = i & 63;           // Wf is [128][64] row-major f32
        wt[d * 128 + k] = f2bf(Wf[i]);
    }
    __syncthreads();

    int wave = tid >> 6, lane = tid & 63;
    int q = lane >> 4, r = lane & 15;
    int e0 = blockIdx.x * 64 + wave * 16;

    int s_r = sidx[e0 + r] & (N_NODES - 1);   // defensive clamp
    int t_r = tidx[e0 + r] & (N_NODES - 1);   (void)t_r;
    const float* xs = x + s_r * D_IN;
    const float* xt = x + (tidx[e0 + r] & (N_NODES - 1)) * D_IN;

    // A operand: lane holds A[m = lane&15][k = q*8 + j]; h = [x[s], x[t]]
    frag8 afr[4];
    float part = 0.0f;
    #pragma unroll
    for (int c = 0; c < 4; ++c) {
        const float* base = (c < 2 ? xs : xt) + (c & 1) * 32 + q * 8;
        int kb = (c >> 1) * 64 + (c & 1) * 32 + q * 8;
        float4 lo = *(const float4*)(base);
        float4 hi = *(const float4*)(base + 4);
        part += lo.x * ww[kb]     + lo.y * ww[kb + 1]
              + lo.z * ww[kb + 2] + lo.w * ww[kb + 3]
              + hi.x * ww[kb + 4] + hi.y * ww[kb + 5]
              + hi.z * ww[kb + 6] + hi.w * ww[kb + 7];
        frag8 f;
        f[0] = (short)f2bf(lo.x); f[1] = (short)f2bf(lo.y);
        f[2] = (short)f2bf(lo.z); f[3] = (short)f2bf(lo.w);
        f[4] = (short)f2bf(hi.x); f[5] = (short)f2bf(hi.y);
        f[6] = (short)f2bf(hi.z); f[7] = (short)f2bf(hi.w);
        afr[c] = f;
    }
    // reduce the score over the 4 lanes sharing r (q = 0..3); afterwards
    // EVERY lane holds the full score for edge e0+r.
    part += __shfl_xor(part, 16);
    part += __shfl_xor(part, 32);
    float ae = expf(part + bw[0]);            // unshifted exp (shift cancels)
    if (lane < 16) ae_out[e0 + r] = ae;       // one writer per edge

    f32x4 acc[4] = { {0,0,0,0}, {0,0,0,0}, {0,0,0,0}, {0,0,0,0} };
    #pragma unroll
    for (int c = 0; c < 4; ++c) {
        #pragma unroll
        for (int dt = 0; dt < 4; ++dt) {
            // B operand: lane holds B[k = q*8+j][n = lane&15] = Wf[k][dt*16+r]
            frag8 bfr = *(const frag8*)(&wt[(dt * 16 + r) * 128 + c * 32 + q * 8]);
            acc[dt] = __builtin_amdgcn_mfma_f32_16x16x32_bf16(afr[c], bfr, acc[dt], 0, 0, 0);
        }
    }

    // C/D layout: col = lane&15 (dim), row = q*4 + reg (edge)
    #pragma unroll
    for (int reg = 0; reg < 4; ++reg) {
        float w = __shfl(ae, q * 4 + reg);    // lane (q*4+reg) holds that edge
        int   e = e0 + q * 4 + reg;
        #pragma unroll
        for (int dt = 0; dt < 4; ++dt) {
            int d = dt * 16 + r;
            float y = acc[dt][reg] + bf[d];
            y = y > 0.0f ? y : 0.0f;
            P[e * D_OUT + d] = y * w;         // 16 lanes -> 64B contiguous
        }
    }
}

// ---------------- per-node gather: out[n] = sum P[e]/ (sum ae + eps) ------
// One block per node. Wave wv scans edges [wv*16384,(wv+1)*16384) as uint4;
// __ballot makes the hit loop wave-uniform (no divergence). No atomics, no
// pre-zeroed state: out is written exactly once per (n,d) per launch.
__global__ void __launch_bounds__(256) k_gather(
        const int* __restrict__ tidx, const float* __restrict__ ae,
        const float* __restrict__ P, float* __restrict__ out) {
    int n  = blockIdx.x;
    int wv = threadIdx.x >> 6, l = threadIdx.x & 63;
    const uint4* t4 = (const uint4*)tidx;
    float acc = 0.0f, asum = 0.0f;
    #pragma unroll 4
    for (int it = 0; it < 64; ++it) {
        int base = wv * 16384 + it * 256;          // edge base of this chunk
        uint4 v = t4[(base >> 2) + l];             // edges base+4l .. +4l+3
        u32 c[4] = { v.x, v.y, v.z, v.w };
        #pragma unroll
        for (int j = 0; j < 4; ++j) {
            u64 m = __ballot(c[j] == (u32)n);
            while (m) {                            // wave-uniform (ballot)
                int b = __ffsll(m) - 1; m &= m - 1;
                int e = base + 4 * b + j;
                asum += ae[e];                     // broadcast load
                acc  += P[e * D_OUT + l];          // coalesced 256B
            }
        }
    }
    __shared__ float red[4][D_OUT];
    __shared__ float reds[4];
    red[wv][l] = acc;
    if (l == 0) reds[wv] = asum;
    __syncthreads();
    if (threadIdx.x < D_OUT) {
        float tot = red[0][l] + red[1][l] + red[2][l] + red[3][l];
        float as  = reds[0] + reds[1] + reds[2] + reds[3];
        out[n * D_OUT + l] = tot / (as + GAT_EPS);
    }
}

extern "C" void kernel_launch(void* const* d_in, const int* in_sizes, int n_in,
                              void* d_out, int out_size, void* d_ws, size_t ws_size,
                              hipStream_t stream) {
    const float* x   = (const float*)d_in[0];
    const float* src = (const float*)d_in[1];
    const float* tgt = (const float*)d_in[2];
    const float* Wf  = (const float*)d_in[3];
    const float* bf  = (const float*)d_in[4];
    const float* Ww  = (const float*)d_in[5];
    const float* bw  = (const float*)d_in[6];
    float* out = (float*)d_out;

    char* ws = (char*)d_ws;
    // ws layout (ALL regions fully written before read, every launch):
    // [sidx 256KB | tidx 256KB | ae 256KB | P 16MB]
    int*   sidx = (int*)  (ws);
    int*   tidx = (int*)  (ws + 262144);
    float* ae   = (float*)(ws + 524288);
    float* P    = (float*)(ws + 786432);

    k_extract<<<4096, 256, 0, stream>>>((const uint4*)src, (const uint4*)tgt,
                                        sidx, tidx);
    k_edges<<<N_EDGES / 64, 256, 0, stream>>>(x, sidx, tidx, Wf, bf, Ww, bw,
                                              ae, P);
    k_gather<<<N_NODES, 256, 0, stream>>>(tidx, ae, P, out);
}